// Round 4
// baseline (380.451 us; speedup 1.0000x reference)
//
#include <hip/hip_runtime.h>

#define GN 50000
#define GE 800000
#define GD 128
#define CAP 64
#define BT 4  // edges per k_build thread (batched-atomic MLP)

typedef unsigned short u16;
typedef unsigned int u32;
typedef short bf16x8 __attribute__((ext_vector_type(8)));
typedef float f32x4 __attribute__((ext_vector_type(4)));
typedef u16 u16x8 __attribute__((ext_vector_type(8)));
typedef u16 u16x4 __attribute__((ext_vector_type(4)));

__device__ inline float bf2f_lo(u32 u) {
  union { u32 i; float f; } v; v.i = u << 16; return v.f;
}
__device__ inline float bf2f_hi(u32 u) {
  union { u32 i; float f; } v; v.i = u & 0xffff0000u; return v.f;
}
__device__ inline u16 f2bf(float f) {  // round-to-nearest-even
  union { float f; u32 i; } v; v.f = f;
  u32 r = v.i + 0x7fffu + ((v.i >> 16) & 1u);
  return (u16)(r >> 16);
}
__device__ inline float rlf(float v, int l) {
  return __int_as_float(__builtin_amdgcn_readlane(__float_as_int(v), l));
}

// ---------------- graph build ----------------
// 4 edges/thread: 4 independent atomicAdds issued before any dependent
// scatter store -> 4x the outstanding-atomic MLP (round-3 k_build was
// one-atomic-per-thread latency-serialized at 46 us). u16 payload halves
// the partial-line writeback traffic (src < 50000 fits u16).
__global__ __launch_bounds__(256) void k_build(const int* __restrict__ src,
                                               const int* __restrict__ dst,
                                               int* __restrict__ cnt,
                                               u16* __restrict__ bucket) {
  const int T = GE / BT;  // 200000 threads
  int t = blockIdx.x * 256 + threadIdx.x;
  if (t >= T) return;
  int s[BT], d[BT], slot[BT];
#pragma unroll
  for (int j = 0; j < BT; j++) {
    int e = t + j * T;  // coalesced within each segment
    s[j] = src[e];
    d[j] = dst[e];
  }
#pragma unroll
  for (int j = 0; j < BT; j++) slot[j] = atomicAdd(&cnt[d[j]], 1);
#pragma unroll
  for (int j = 0; j < BT; j++)
    if (slot[j] < CAP) bucket[d[j] * CAP + slot[j]] = (u16)s[j];
}

__global__ __launch_bounds__(256) void k_dinv(const int* __restrict__ cnt,
                                              float* __restrict__ dinv) {
  int i = blockIdx.x * 256 + threadIdx.x;
  if (i >= GN) return;
  dinv[i] = rsqrtf((float)(cnt[i] + 1));  // +1 self-loop
}

// Cast W (128x128 f32, W[k][n]) into MFMA B-fragment order:
// frag (kq,cb,lane), j-th elem = W[kq*32 + (lane>>4)*8 + j][cb*16 + (lane&15)]
// stored at Wf[((kq*8+cb)*64 + lane)*8 + j].
__global__ __launch_bounds__(256) void k_prep(const float* __restrict__ W0,
                                              const float* __restrict__ W1,
                                              u16* __restrict__ Wf0,
                                              u16* __restrict__ Wf1) {
  int idx = blockIdx.x * 256 + threadIdx.x;  // 0..4095
  const float* W = (idx & 2048) ? W1 : W0;
  u16* Wf = (idx & 2048) ? Wf1 : Wf0;
  int r = idx & 2047;
  int kq = r >> 9, cb = (r >> 6) & 7, lane = r & 63;
  int m16 = lane & 15, quad = lane >> 4;
  int k0 = kq * 32 + quad * 8;
  int n = cb * 16 + m16;
  u16x8 o;
#pragma unroll
  for (int j = 0; j < 8; j++) o[j] = f2bf(W[(k0 + j) * 128 + n]);
  *(u16x8*)&Wf[((kq * 8 + cb) * 64 + lane) * 8] = o;
}

// ---------------- bf16 MFMA GEMM: H[GN][128] = X @ W ----------------
// Block: 256 thr = 4 waves over a 64-row x 128-col tile. Wave w: 64 rows x
// cols [32w,32w+32) as 4x2 tiles of 16x16x32. B-frags live in registers;
// only the X tile goes through LDS (17.4 KB -> high occupancy).
template <bool IN_F32>
__global__ __launch_bounds__(256, 4) void k_gemm(const void* __restrict__ Xin,
                                                 const u16* __restrict__ Wf,
                                                 u16* __restrict__ H) {
  __shared__ u16 Xs[64][136];  // pad: row stride 272B, 16B-aligned frag reads
  int t = threadIdx.x;
  int lane = t & 63, wave = t >> 6;
  int m16 = lane & 15, quad = lane >> 4;
  int r0 = blockIdx.x * 64;

  bf16x8 bfr[4][2];
#pragma unroll
  for (int kq = 0; kq < 4; kq++)
#pragma unroll
    for (int c = 0; c < 2; c++)
      bfr[kq][c] = *(const bf16x8*)&Wf[((kq * 8 + wave * 2 + c) * 64 + lane) * 8];

  if (IN_F32) {  // stage + cast X tile (64 rows x 128 f32)
    const float4* Xv = (const float4*)Xin;
#pragma unroll
    for (int i = 0; i < 8; i++) {
      int idx = i * 256 + t;
      int row = idx >> 5, c4 = idx & 31;
      int gr = r0 + row; if (gr >= GN) gr = GN - 1;  // clamp; stores guarded
      float4 v = Xv[(size_t)gr * 32 + c4];
      u16x4 u; u.x = f2bf(v.x); u.y = f2bf(v.y); u.z = f2bf(v.z); u.w = f2bf(v.w);
      *(u16x4*)&Xs[row][c4 * 4] = u;
    }
  } else {  // bf16 input: straight u16x8 copy
    const u16x8* Xv = (const u16x8*)Xin;
#pragma unroll
    for (int i = 0; i < 4; i++) {
      int idx = i * 256 + t;
      int row = idx >> 4, c8 = idx & 15;
      int gr = r0 + row; if (gr >= GN) gr = GN - 1;
      *(u16x8*)&Xs[row][c8 * 8] = Xv[(size_t)gr * 16 + c8];
    }
  }
  __syncthreads();

  f32x4 acc[4][2] = {};
#pragma unroll
  for (int kq = 0; kq < 4; kq++) {
#pragma unroll
    for (int rb = 0; rb < 4; rb++) {
      bf16x8 a = *(const bf16x8*)&Xs[rb * 16 + m16][kq * 32 + quad * 8];
      acc[rb][0] = __builtin_amdgcn_mfma_f32_16x16x32_bf16(a, bfr[kq][0], acc[rb][0], 0, 0, 0);
      acc[rb][1] = __builtin_amdgcn_mfma_f32_16x16x32_bf16(a, bfr[kq][1], acc[rb][1], 0, 0, 0);
    }
  }

#pragma unroll
  for (int rb = 0; rb < 4; rb++) {
#pragma unroll
    for (int i = 0; i < 4; i++) {
      int grow = r0 + rb * 16 + quad * 4 + i;
      if (grow < GN) {
#pragma unroll
        for (int c = 0; c < 2; c++)
          H[(size_t)grow * 128 + (wave * 2 + c) * 16 + m16] = f2bf(acc[rb][c][i]);
      }
    }
  }
}

// ---------------- aggregation (bf16 H rows, 256B gathers) ----------------
// One wave per node. Per-edge src/weight via readlane (uniform loop index ->
// scalar regs). 16 independent row-gathers in flight per iteration; pad lanes
// (weight 0) gather row 0, which is L1-resident in every CU -> near-free.
template <bool FINAL>  // FINAL: f32 out, no relu. else: bf16 out + relu.
__global__ __launch_bounds__(256) void k_agg(const u16* __restrict__ H,
                                             const u16* __restrict__ bucket,
                                             const int* __restrict__ cnt,
                                             const float* __restrict__ dinv,
                                             const float* __restrict__ bias,
                                             void* __restrict__ out) {
  int wid = (blockIdx.x * 256 + threadIdx.x) >> 6;
  int lane = threadIdx.x & 63;
  if (wid >= GN) return;

  float dv = dinv[wid];
  int deg = min(cnt[wid], CAP);

  int s_l = 0;
  float d_l = 0.f;
  if (lane < deg) {  // coalesced preload; padded lanes: row 0 with weight 0
    s_l = (int)bucket[wid * CAP + lane];
    d_l = dinv[s_l];
  }

  const u32* Hv = (const u32*)H;  // 64 u32 per 128-bf16 row
  u32 hs = Hv[(size_t)wid * 64 + lane];
  float ax = dv * bf2f_lo(hs);
  float ay = dv * bf2f_hi(hs);
  float2 bb = ((const float2*)bias)[lane];

  int dpad = (deg + 15) & ~15;
  for (int i = 0; i < dpad; i += 16) {
    int ss[16];
    u32 hh[16];
    float ww[16];
#pragma unroll
    for (int j = 0; j < 16; j++) ss[j] = __builtin_amdgcn_readlane(s_l, i + j);
#pragma unroll
    for (int j = 0; j < 16; j++) hh[j] = Hv[(size_t)ss[j] * 64 + lane];
#pragma unroll
    for (int j = 0; j < 16; j++) ww[j] = rlf(d_l, i + j);
#pragma unroll
    for (int j = 0; j < 16; j++) {
      ax += ww[j] * bf2f_lo(hh[j]);
      ay += ww[j] * bf2f_hi(hh[j]);
    }
  }

  float ox = dv * ax + bb.x;
  float oy = dv * ay + bb.y;
  if (!FINAL) {
    ox = fmaxf(ox, 0.f); oy = fmaxf(oy, 0.f);
    u32 packed = ((u32)f2bf(oy) << 16) | (u32)f2bf(ox);
    ((u32*)out)[(size_t)wid * 64 + lane] = packed;
  } else {
    ((float2*)out)[(size_t)wid * 64 + lane] = make_float2(ox, oy);
  }
}

extern "C" void kernel_launch(void* const* d_in, const int* in_sizes, int n_in,
                              void* d_out, int out_size, void* d_ws, size_t ws_size,
                              hipStream_t stream) {
  const float* x1 = (const float*)d_in[0];
  const int* ei1  = (const int*)d_in[1];
  const float* x2 = (const float*)d_in[2];
  const int* ei2  = (const int*)d_in[3];
  const float* W0 = (const float*)d_in[4];
  const float* b0 = (const float*)d_in[5];
  const float* W1 = (const float*)d_in[6];
  const float* b1 = (const float*)d_in[7];
  float* out = (float*)d_out;

  char* ws = (char*)d_ws;
  size_t off = 0;
  auto carve = [&](size_t bytes) -> char* {
    char* p = ws + off;
    off = (off + bytes + 511) & ~(size_t)511;
    return p;
  };
  int* cnt    = (int*)carve((size_t)GN * 4);
  float* dinv = (float*)carve((size_t)GN * 4);
  u16* bucket = (u16*)carve((size_t)GN * CAP * 2);   // 6.4 MB (u16 src ids)
  u16* h      = (u16*)carve((size_t)GN * GD * 2);    // 12.8 MB bf16
  u16* a      = (u16*)carve((size_t)GN * GD * 2);    // 12.8 MB bf16
  u16* W0f    = (u16*)carve((size_t)GD * GD * 2);
  u16* W1f    = (u16*)carve((size_t)GD * GD * 2);

  k_prep<<<16, 256, 0, stream>>>(W0, W1, W0f, W1f);

  for (int g = 0; g < 2; g++) {
    const float* x = g ? x2 : x1;
    const int* src = g ? ei2 : ei1;
    const int* dst = src + GE;
    float* z = out + (size_t)g * GN * GD;

    hipMemsetAsync(cnt, 0, (size_t)GN * 4, stream);
    k_build<<<(GE / BT + 255) / 256, 256, 0, stream>>>(src, dst, cnt, bucket);
    k_dinv<<<(GN + 255) / 256, 256, 0, stream>>>(cnt, dinv);

    // Layer 1: a = relu(Ahat * (x @ W0) + b0)   [a in bf16]
    k_gemm<true><<<(GN + 63) / 64, 256, 0, stream>>>(x, W0f, h);
    k_agg<false><<<(GN * 64 + 255) / 256, 256, 0, stream>>>(h, bucket, cnt, dinv, b0, a);

    // Layer 2: z = Ahat * (a @ W1) + b1          [z in f32 -> d_out]
    k_gemm<false><<<(GN + 63) / 64, 256, 0, stream>>>(a, W1f, h);
    k_agg<true><<<(GN * 64 + 255) / 256, 256, 0, stream>>>(h, bucket, cnt, dinv, b1, z);
  }
}

// Round 5
// 373.219 us; speedup vs baseline: 1.0194x; 1.0194x over previous
//
#include <hip/hip_runtime.h>

#define GN 50000
#define GE 800000
#define GD 128
#define CAP 64

typedef unsigned short u16;
typedef unsigned int u32;
typedef short bf16x8 __attribute__((ext_vector_type(8)));
typedef float f32x4 __attribute__((ext_vector_type(4)));
typedef u16 u16x8 __attribute__((ext_vector_type(8)));
typedef u16 u16x4 __attribute__((ext_vector_type(4)));

__device__ inline float bf2f_lo(u32 u) {
  union { u32 i; float f; } v; v.i = u << 16; return v.f;
}
__device__ inline float bf2f_hi(u32 u) {
  union { u32 i; float f; } v; v.i = u & 0xffff0000u; return v.f;
}
__device__ inline u16 f2bf(float f) {  // round-to-nearest-even
  union { float f; u32 i; } v; v.f = f;
  u32 r = v.i + 0x7fffu + ((v.i >> 16) & 1u);
  return (u16)(r >> 16);
}
__device__ inline float rlf(float v, int l) {
  return __int_as_float(__builtin_amdgcn_readlane(__float_as_int(v), l));
}

// ---------------- graph build ----------------
// 1 edge/thread (round-3 config: max request concurrency — round 4 proved
// batching per-thread REDUCES throughput by cutting thread count).
// Nontemporal scatter store: the round-3/4 wall was ~45 MB of partial-line
// L2 writebacks (57 B/edge for 2 B of payload). NT streams the 2 B through
// without dirtying an L2 line. NT loads: edge stream has zero reuse.
__global__ __launch_bounds__(256) void k_build(const int* __restrict__ src,
                                               const int* __restrict__ dst,
                                               int* __restrict__ cnt,
                                               u16* __restrict__ bucket) {
  int e = blockIdx.x * 256 + threadIdx.x;
  if (e >= GE) return;
  int s = __builtin_nontemporal_load(&src[e]);
  int d = __builtin_nontemporal_load(&dst[e]);
  int slot = atomicAdd(&cnt[d], 1);
  if (slot < CAP)
    __builtin_nontemporal_store((u16)s, &bucket[d * CAP + slot]);
}

__global__ __launch_bounds__(256) void k_dinv(const int* __restrict__ cnt,
                                              float* __restrict__ dinv) {
  int i = blockIdx.x * 256 + threadIdx.x;
  if (i >= GN) return;
  dinv[i] = rsqrtf((float)(cnt[i] + 1));  // +1 self-loop
}

// Cast W (128x128 f32, W[k][n]) into MFMA B-fragment order:
// frag (kq,cb,lane), j-th elem = W[kq*32 + (lane>>4)*8 + j][cb*16 + (lane&15)]
// stored at Wf[((kq*8+cb)*64 + lane)*8 + j].
__global__ __launch_bounds__(256) void k_prep(const float* __restrict__ W0,
                                              const float* __restrict__ W1,
                                              u16* __restrict__ Wf0,
                                              u16* __restrict__ Wf1) {
  int idx = blockIdx.x * 256 + threadIdx.x;  // 0..4095
  const float* W = (idx & 2048) ? W1 : W0;
  u16* Wf = (idx & 2048) ? Wf1 : Wf0;
  int r = idx & 2047;
  int kq = r >> 9, cb = (r >> 6) & 7, lane = r & 63;
  int m16 = lane & 15, quad = lane >> 4;
  int k0 = kq * 32 + quad * 8;
  int n = cb * 16 + m16;
  u16x8 o;
#pragma unroll
  for (int j = 0; j < 8; j++) o[j] = f2bf(W[(k0 + j) * 128 + n]);
  *(u16x8*)&Wf[((kq * 8 + cb) * 64 + lane) * 8] = o;
}

// ---------------- bf16 MFMA GEMM: H[GN][128] = X @ W ----------------
// Block: 256 thr = 4 waves over a 64-row x 128-col tile. Wave w: 64 rows x
// cols [32w,32w+32) as 4x2 tiles of 16x16x32. B-frags live in registers;
// only the X tile goes through LDS (17.4 KB -> high occupancy).
template <bool IN_F32>
__global__ __launch_bounds__(256, 4) void k_gemm(const void* __restrict__ Xin,
                                                 const u16* __restrict__ Wf,
                                                 u16* __restrict__ H) {
  __shared__ u16 Xs[64][136];  // pad: row stride 272B, 16B-aligned frag reads
  int t = threadIdx.x;
  int lane = t & 63, wave = t >> 6;
  int m16 = lane & 15, quad = lane >> 4;
  int r0 = blockIdx.x * 64;

  bf16x8 bfr[4][2];
#pragma unroll
  for (int kq = 0; kq < 4; kq++)
#pragma unroll
    for (int c = 0; c < 2; c++)
      bfr[kq][c] = *(const bf16x8*)&Wf[((kq * 8 + wave * 2 + c) * 64 + lane) * 8];

  if (IN_F32) {  // stage + cast X tile (64 rows x 128 f32)
    const float4* Xv = (const float4*)Xin;
#pragma unroll
    for (int i = 0; i < 8; i++) {
      int idx = i * 256 + t;
      int row = idx >> 5, c4 = idx & 31;
      int gr = r0 + row; if (gr >= GN) gr = GN - 1;  // clamp; stores guarded
      float4 v = Xv[(size_t)gr * 32 + c4];
      u16x4 u; u.x = f2bf(v.x); u.y = f2bf(v.y); u.z = f2bf(v.z); u.w = f2bf(v.w);
      *(u16x4*)&Xs[row][c4 * 4] = u;
    }
  } else {  // bf16 input: straight u16x8 copy
    const u16x8* Xv = (const u16x8*)Xin;
#pragma unroll
    for (int i = 0; i < 4; i++) {
      int idx = i * 256 + t;
      int row = idx >> 4, c8 = idx & 15;
      int gr = r0 + row; if (gr >= GN) gr = GN - 1;
      *(u16x8*)&Xs[row][c8 * 8] = Xv[(size_t)gr * 16 + c8];
    }
  }
  __syncthreads();

  f32x4 acc[4][2] = {};
#pragma unroll
  for (int kq = 0; kq < 4; kq++) {
#pragma unroll
    for (int rb = 0; rb < 4; rb++) {
      bf16x8 a = *(const bf16x8*)&Xs[rb * 16 + m16][kq * 32 + quad * 8];
      acc[rb][0] = __builtin_amdgcn_mfma_f32_16x16x32_bf16(a, bfr[kq][0], acc[rb][0], 0, 0, 0);
      acc[rb][1] = __builtin_amdgcn_mfma_f32_16x16x32_bf16(a, bfr[kq][1], acc[rb][1], 0, 0, 0);
    }
  }

#pragma unroll
  for (int rb = 0; rb < 4; rb++) {
#pragma unroll
    for (int i = 0; i < 4; i++) {
      int grow = r0 + rb * 16 + quad * 4 + i;
      if (grow < GN) {
#pragma unroll
        for (int c = 0; c < 2; c++)
          H[(size_t)grow * 128 + (wave * 2 + c) * 16 + m16] = f2bf(acc[rb][c][i]);
      }
    }
  }
}

// ---------------- aggregation (bf16 H rows, 256B gathers) ----------------
// One wave per node. Per-edge src/weight via readlane (uniform loop index ->
// scalar regs). 16 independent row-gathers in flight per iteration; pad lanes
// (weight 0) gather row 0, which is L1-resident in every CU -> near-free.
template <bool FINAL>  // FINAL: f32 out, no relu. else: bf16 out + relu.
__global__ __launch_bounds__(256) void k_agg(const u16* __restrict__ H,
                                             const u16* __restrict__ bucket,
                                             const int* __restrict__ cnt,
                                             const float* __restrict__ dinv,
                                             const float* __restrict__ bias,
                                             void* __restrict__ out) {
  int wid = (blockIdx.x * 256 + threadIdx.x) >> 6;
  int lane = threadIdx.x & 63;
  if (wid >= GN) return;

  float dv = dinv[wid];
  int deg = min(cnt[wid], CAP);

  int s_l = 0;
  float d_l = 0.f;
  if (lane < deg) {  // coalesced preload; padded lanes: row 0 with weight 0
    s_l = (int)bucket[wid * CAP + lane];
    d_l = dinv[s_l];
  }

  const u32* Hv = (const u32*)H;  // 64 u32 per 128-bf16 row
  u32 hs = Hv[(size_t)wid * 64 + lane];
  float ax = dv * bf2f_lo(hs);
  float ay = dv * bf2f_hi(hs);
  float2 bb = ((const float2*)bias)[lane];

  int dpad = (deg + 15) & ~15;
  for (int i = 0; i < dpad; i += 16) {
    int ss[16];
    u32 hh[16];
    float ww[16];
#pragma unroll
    for (int j = 0; j < 16; j++) ss[j] = __builtin_amdgcn_readlane(s_l, i + j);
#pragma unroll
    for (int j = 0; j < 16; j++) hh[j] = Hv[(size_t)ss[j] * 64 + lane];
#pragma unroll
    for (int j = 0; j < 16; j++) ww[j] = rlf(d_l, i + j);
#pragma unroll
    for (int j = 0; j < 16; j++) {
      ax += ww[j] * bf2f_lo(hh[j]);
      ay += ww[j] * bf2f_hi(hh[j]);
    }
  }

  float ox = dv * ax + bb.x;
  float oy = dv * ay + bb.y;
  if (!FINAL) {
    ox = fmaxf(ox, 0.f); oy = fmaxf(oy, 0.f);
    u32 packed = ((u32)f2bf(oy) << 16) | (u32)f2bf(ox);
    ((u32*)out)[(size_t)wid * 64 + lane] = packed;
  } else {
    ((float2*)out)[(size_t)wid * 64 + lane] = make_float2(ox, oy);
  }
}

extern "C" void kernel_launch(void* const* d_in, const int* in_sizes, int n_in,
                              void* d_out, int out_size, void* d_ws, size_t ws_size,
                              hipStream_t stream) {
  const float* x1 = (const float*)d_in[0];
  const int* ei1  = (const int*)d_in[1];
  const float* x2 = (const float*)d_in[2];
  const int* ei2  = (const int*)d_in[3];
  const float* W0 = (const float*)d_in[4];
  const float* b0 = (const float*)d_in[5];
  const float* W1 = (const float*)d_in[6];
  const float* b1 = (const float*)d_in[7];
  float* out = (float*)d_out;

  char* ws = (char*)d_ws;
  size_t off = 0;
  auto carve = [&](size_t bytes) -> char* {
    char* p = ws + off;
    off = (off + bytes + 511) & ~(size_t)511;
    return p;
  };
  int* cnt    = (int*)carve((size_t)GN * 4);
  float* dinv = (float*)carve((size_t)GN * 4);
  u16* bucket = (u16*)carve((size_t)GN * CAP * 2);   // 6.4 MB (u16 src ids)
  u16* h      = (u16*)carve((size_t)GN * GD * 2);    // 12.8 MB bf16
  u16* a      = (u16*)carve((size_t)GN * GD * 2);    // 12.8 MB bf16
  u16* W0f    = (u16*)carve((size_t)GD * GD * 2);
  u16* W1f    = (u16*)carve((size_t)GD * GD * 2);

  k_prep<<<16, 256, 0, stream>>>(W0, W1, W0f, W1f);

  for (int g = 0; g < 2; g++) {
    const float* x = g ? x2 : x1;
    const int* src = g ? ei2 : ei1;
    const int* dst = src + GE;
    float* z = out + (size_t)g * GN * GD;

    hipMemsetAsync(cnt, 0, (size_t)GN * 4, stream);
    k_build<<<(GE + 255) / 256, 256, 0, stream>>>(src, dst, cnt, bucket);
    k_dinv<<<(GN + 255) / 256, 256, 0, stream>>>(cnt, dinv);

    // Layer 1: a = relu(Ahat * (x @ W0) + b0)   [a in bf16]
    k_gemm<true><<<(GN + 63) / 64, 256, 0, stream>>>(x, W0f, h);
    k_agg<false><<<(GN * 64 + 255) / 256, 256, 0, stream>>>(h, bucket, cnt, dinv, b0, a);

    // Layer 2: z = Ahat * (a @ W1) + b1          [z in f32 -> d_out]
    k_gemm<false><<<(GN + 63) / 64, 256, 0, stream>>>(a, W1f, h);
    k_agg<true><<<(GN * 64 + 255) / 256, 256, 0, stream>>>(h, bucket, cnt, dinv, b1, z);
  }
}

// Round 6
// 361.670 us; speedup vs baseline: 1.0519x; 1.0319x over previous
//
#include <hip/hip_runtime.h>

#define GN 50000
#define GE 800000
#define GD 128
#define CAP 64
#define NBIN 8
#define BINW 6250  // ceil(GN/NBIN)
#define NCHUNK 400 // blocks per bin

typedef unsigned short u16;
typedef unsigned int u32;
typedef short bf16x8 __attribute__((ext_vector_type(8)));
typedef float f32x4 __attribute__((ext_vector_type(4)));
typedef u16 u16x8 __attribute__((ext_vector_type(8)));
typedef u16 u16x4 __attribute__((ext_vector_type(4)));

__device__ inline float bf2f_lo(u32 u) {
  union { u32 i; float f; } v; v.i = u << 16; return v.f;
}
__device__ inline float bf2f_hi(u32 u) {
  union { u32 i; float f; } v; v.i = u & 0xffff0000u; return v.f;
}
__device__ inline u16 f2bf(float f) {  // round-to-nearest-even
  union { float f; u32 i; } v; v.f = f;
  u32 r = v.i + 0x7fffu + ((v.i >> 16) & 1u);
  return (u16)(r >> 16);
}
__device__ inline float rlf(float v, int l) {
  return __int_as_float(__builtin_amdgcn_readlane(__float_as_int(v), l));
}

// ---------------- graph build, XCD-localized ----------------
// Round 3-5 k_build was coherence-bound: cnt/bucket lines received atomics
// and stores from random CUs on all 8 non-coherent XCD L2s -> per-edge line
// ping-pong (57 B/edge HBM, serialized ownership migration, every pipe idle).
// Fix: bin = dst/6250; bin == blockIdx&7, which round-robins to one XCD per
// bin -> every cnt/bucket line has a single L2 owner. Each block reads its
// full edge chunk (8x re-read, sequential, cheap) and commits only its bin.
// Correctness does not depend on the XCD mapping (binning only filters).
__global__ __launch_bounds__(256) void k_build(const int* __restrict__ src,
                                               const int* __restrict__ dst,
                                               int* __restrict__ cnt,
                                               u16* __restrict__ bucket) {
  int bin = blockIdx.x & (NBIN - 1);
  int chunk = blockIdx.x >> 3;  // 0..NCHUNK-1
  int t0 = chunk * 256 + threadIdx.x;
  const int stride = NCHUNK * 256;
  for (int e = t0; e < GE; e += stride) {
    int d = __builtin_nontemporal_load(&dst[e]);
    int s = __builtin_nontemporal_load(&src[e]);
    if (d / BINW == bin) {
      int slot = atomicAdd(&cnt[d], 1);
      if (slot < CAP) bucket[d * CAP + slot] = (u16)s;
    }
  }
}

__global__ __launch_bounds__(256) void k_dinv(const int* __restrict__ cnt,
                                              float* __restrict__ dinv) {
  int i = blockIdx.x * 256 + threadIdx.x;
  if (i >= GN) return;
  dinv[i] = rsqrtf((float)(cnt[i] + 1));  // +1 self-loop
}

// Cast W (128x128 f32, W[k][n]) into MFMA B-fragment order:
// frag (kq,cb,lane), j-th elem = W[kq*32 + (lane>>4)*8 + j][cb*16 + (lane&15)]
// stored at Wf[((kq*8+cb)*64 + lane)*8 + j].
__global__ __launch_bounds__(256) void k_prep(const float* __restrict__ W0,
                                              const float* __restrict__ W1,
                                              u16* __restrict__ Wf0,
                                              u16* __restrict__ Wf1) {
  int idx = blockIdx.x * 256 + threadIdx.x;  // 0..4095
  const float* W = (idx & 2048) ? W1 : W0;
  u16* Wf = (idx & 2048) ? Wf1 : Wf0;
  int r = idx & 2047;
  int kq = r >> 9, cb = (r >> 6) & 7, lane = r & 63;
  int m16 = lane & 15, quad = lane >> 4;
  int k0 = kq * 32 + quad * 8;
  int n = cb * 16 + m16;
  u16x8 o;
#pragma unroll
  for (int j = 0; j < 8; j++) o[j] = f2bf(W[(k0 + j) * 128 + n]);
  *(u16x8*)&Wf[((kq * 8 + cb) * 64 + lane) * 8] = o;
}

// ---------------- bf16 MFMA GEMM: H[GN][128] = X @ W ----------------
// Block: 256 thr = 4 waves over a 64-row x 128-col tile. Wave w: 64 rows x
// cols [32w,32w+32) as 4x2 tiles of 16x16x32. B-frags live in registers;
// only the X tile goes through LDS (17.4 KB -> high occupancy).
template <bool IN_F32>
__global__ __launch_bounds__(256, 4) void k_gemm(const void* __restrict__ Xin,
                                                 const u16* __restrict__ Wf,
                                                 u16* __restrict__ H) {
  __shared__ u16 Xs[64][136];  // pad: row stride 272B, 16B-aligned frag reads
  int t = threadIdx.x;
  int lane = t & 63, wave = t >> 6;
  int m16 = lane & 15, quad = lane >> 4;
  int r0 = blockIdx.x * 64;

  bf16x8 bfr[4][2];
#pragma unroll
  for (int kq = 0; kq < 4; kq++)
#pragma unroll
    for (int c = 0; c < 2; c++)
      bfr[kq][c] = *(const bf16x8*)&Wf[((kq * 8 + wave * 2 + c) * 64 + lane) * 8];

  if (IN_F32) {  // stage + cast X tile (64 rows x 128 f32)
    const float4* Xv = (const float4*)Xin;
#pragma unroll
    for (int i = 0; i < 8; i++) {
      int idx = i * 256 + t;
      int row = idx >> 5, c4 = idx & 31;
      int gr = r0 + row; if (gr >= GN) gr = GN - 1;  // clamp; stores guarded
      float4 v = Xv[(size_t)gr * 32 + c4];
      u16x4 u; u.x = f2bf(v.x); u.y = f2bf(v.y); u.z = f2bf(v.z); u.w = f2bf(v.w);
      *(u16x4*)&Xs[row][c4 * 4] = u;
    }
  } else {  // bf16 input: straight u16x8 copy
    const u16x8* Xv = (const u16x8*)Xin;
#pragma unroll
    for (int i = 0; i < 4; i++) {
      int idx = i * 256 + t;
      int row = idx >> 4, c8 = idx & 15;
      int gr = r0 + row; if (gr >= GN) gr = GN - 1;
      *(u16x8*)&Xs[row][c8 * 8] = Xv[(size_t)gr * 16 + c8];
    }
  }
  __syncthreads();

  f32x4 acc[4][2] = {};
#pragma unroll
  for (int kq = 0; kq < 4; kq++) {
#pragma unroll
    for (int rb = 0; rb < 4; rb++) {
      bf16x8 a = *(const bf16x8*)&Xs[rb * 16 + m16][kq * 32 + quad * 8];
      acc[rb][0] = __builtin_amdgcn_mfma_f32_16x16x32_bf16(a, bfr[kq][0], acc[rb][0], 0, 0, 0);
      acc[rb][1] = __builtin_amdgcn_mfma_f32_16x16x32_bf16(a, bfr[kq][1], acc[rb][1], 0, 0, 0);
    }
  }

#pragma unroll
  for (int rb = 0; rb < 4; rb++) {
#pragma unroll
    for (int i = 0; i < 4; i++) {
      int grow = r0 + rb * 16 + quad * 4 + i;
      if (grow < GN) {
#pragma unroll
        for (int c = 0; c < 2; c++)
          H[(size_t)grow * 128 + (wave * 2 + c) * 16 + m16] = f2bf(acc[rb][c][i]);
      }
    }
  }
}

// ---------------- aggregation (bf16 H rows, 256B gathers) ----------------
// One wave per node. Per-edge src/weight via readlane (uniform loop index ->
// scalar regs). 16 independent row-gathers in flight per iteration; pad lanes
// (weight 0) gather row 0, which is L1-resident in every CU -> near-free.
template <bool FINAL>  // FINAL: f32 out, no relu. else: bf16 out + relu.
__global__ __launch_bounds__(256) void k_agg(const u16* __restrict__ H,
                                             const u16* __restrict__ bucket,
                                             const int* __restrict__ cnt,
                                             const float* __restrict__ dinv,
                                             const float* __restrict__ bias,
                                             void* __restrict__ out) {
  int wid = (blockIdx.x * 256 + threadIdx.x) >> 6;
  int lane = threadIdx.x & 63;
  if (wid >= GN) return;

  float dv = dinv[wid];
  int deg = min(cnt[wid], CAP);

  int s_l = 0;
  float d_l = 0.f;
  if (lane < deg) {  // coalesced preload; padded lanes: row 0 with weight 0
    s_l = (int)bucket[wid * CAP + lane];
    d_l = dinv[s_l];
  }

  const u32* Hv = (const u32*)H;  // 64 u32 per 128-bf16 row
  u32 hs = Hv[(size_t)wid * 64 + lane];
  float ax = dv * bf2f_lo(hs);
  float ay = dv * bf2f_hi(hs);
  float2 bb = ((const float2*)bias)[lane];

  int dpad = (deg + 15) & ~15;
  for (int i = 0; i < dpad; i += 16) {
    int ss[16];
    u32 hh[16];
    float ww[16];
#pragma unroll
    for (int j = 0; j < 16; j++) ss[j] = __builtin_amdgcn_readlane(s_l, i + j);
#pragma unroll
    for (int j = 0; j < 16; j++) hh[j] = Hv[(size_t)ss[j] * 64 + lane];
#pragma unroll
    for (int j = 0; j < 16; j++) ww[j] = rlf(d_l, i + j);
#pragma unroll
    for (int j = 0; j < 16; j++) {
      ax += ww[j] * bf2f_lo(hh[j]);
      ay += ww[j] * bf2f_hi(hh[j]);
    }
  }

  float ox = dv * ax + bb.x;
  float oy = dv * ay + bb.y;
  if (!FINAL) {
    ox = fmaxf(ox, 0.f); oy = fmaxf(oy, 0.f);
    u32 packed = ((u32)f2bf(oy) << 16) | (u32)f2bf(ox);
    ((u32*)out)[(size_t)wid * 64 + lane] = packed;
  } else {
    ((float2*)out)[(size_t)wid * 64 + lane] = make_float2(ox, oy);
  }
}

extern "C" void kernel_launch(void* const* d_in, const int* in_sizes, int n_in,
                              void* d_out, int out_size, void* d_ws, size_t ws_size,
                              hipStream_t stream) {
  const float* x1 = (const float*)d_in[0];
  const int* ei1  = (const int*)d_in[1];
  const float* x2 = (const float*)d_in[2];
  const int* ei2  = (const int*)d_in[3];
  const float* W0 = (const float*)d_in[4];
  const float* b0 = (const float*)d_in[5];
  const float* W1 = (const float*)d_in[6];
  const float* b1 = (const float*)d_in[7];
  float* out = (float*)d_out;

  char* ws = (char*)d_ws;
  size_t off = 0;
  auto carve = [&](size_t bytes) -> char* {
    char* p = ws + off;
    off = (off + bytes + 511) & ~(size_t)511;
    return p;
  };
  int* cnt    = (int*)carve((size_t)GN * 4);
  float* dinv = (float*)carve((size_t)GN * 4);
  u16* bucket = (u16*)carve((size_t)GN * CAP * 2);   // 6.4 MB (u16 src ids)
  u16* h      = (u16*)carve((size_t)GN * GD * 2);    // 12.8 MB bf16
  u16* a      = (u16*)carve((size_t)GN * GD * 2);    // 12.8 MB bf16
  u16* W0f    = (u16*)carve((size_t)GD * GD * 2);
  u16* W1f    = (u16*)carve((size_t)GD * GD * 2);

  k_prep<<<16, 256, 0, stream>>>(W0, W1, W0f, W1f);

  for (int g = 0; g < 2; g++) {
    const float* x = g ? x2 : x1;
    const int* src = g ? ei2 : ei1;
    const int* dst = src + GE;
    float* z = out + (size_t)g * GN * GD;

    hipMemsetAsync(cnt, 0, (size_t)GN * 4, stream);
    k_build<<<NBIN * NCHUNK, 256, 0, stream>>>(src, dst, cnt, bucket);
    k_dinv<<<(GN + 255) / 256, 256, 0, stream>>>(cnt, dinv);

    // Layer 1: a = relu(Ahat * (x @ W0) + b0)   [a in bf16]
    k_gemm<true><<<(GN + 63) / 64, 256, 0, stream>>>(x, W0f, h);
    k_agg<false><<<(GN * 64 + 255) / 256, 256, 0, stream>>>(h, bucket, cnt, dinv, b0, a);

    // Layer 2: z = Ahat * (a @ W1) + b1          [z in f32 -> d_out]
    k_gemm<false><<<(GN + 63) / 64, 256, 0, stream>>>(a, W1f, h);
    k_agg<true><<<(GN * 64 + 255) / 256, 256, 0, stream>>>(h, bucket, cnt, dinv, b1, z);
  }
}

// Round 7
// 327.046 us; speedup vs baseline: 1.1633x; 1.1059x over previous
//
#include <hip/hip_runtime.h>

#define GN 50000
#define GE 800000
#define GD 128
#define CAP 64
#define NBIN 8
#define BINW 6250   // BINW*NBIN == GN exactly
#define NCHUNK 400  // blocks per bin (per graph)

typedef unsigned short u16;
typedef unsigned int u32;
typedef short bf16x8 __attribute__((ext_vector_type(8)));
typedef float f32x4 __attribute__((ext_vector_type(4)));
typedef u16 u16x8 __attribute__((ext_vector_type(8)));
typedef u16 u16x4 __attribute__((ext_vector_type(4)));

__device__ inline float bf2f_lo(u32 u) {
  union { u32 i; float f; } v; v.i = u << 16; return v.f;
}
__device__ inline float bf2f_hi(u32 u) {
  union { u32 i; float f; } v; v.i = u & 0xffff0000u; return v.f;
}
__device__ inline u16 f2bf(float f) {  // round-to-nearest-even
  union { float f; u32 i; } v; v.f = f;
  u32 r = v.i + 0x7fffu + ((v.i >> 16) & 1u);
  return (u16)(r >> 16);
}
__device__ inline float rlf(float v, int l) {
  return __int_as_float(__builtin_amdgcn_readlane(__float_as_int(v), l));
}

// ---------------- graph build: BOTH graphs, one dispatch ----------------
// XCD-localized bins (round 6: halved writeback, single L2 owner per line).
// New: (a) both graphs in one grid — the two 45us latency-bound dispatches
// overlap; (b) all 8 per-thread edge loads issued before any commit (16
// loads in flight vs 2 — the serial load->atomic loop was the residual).
__global__ __launch_bounds__(256) void k_build(const int* __restrict__ e1,
                                               const int* __restrict__ e2,
                                               int* __restrict__ cnt,
                                               u16* __restrict__ bucket) {
  const int half = NBIN * NCHUNK;  // 3200 blocks per graph
  int gb = blockIdx.x >= half;
  int bid = blockIdx.x - gb * half;
  const int* E = gb ? e2 : e1;
  const int* src = E;
  const int* dst = E + GE;
  int* c = cnt + gb * GN;
  u16* bk = bucket + (size_t)gb * GN * CAP;

  int bin = bid & (NBIN - 1);
  int chunk = bid >> 3;
  int t0 = chunk * 256 + threadIdx.x;
  const int stride = NCHUNK * 256;  // 102400
  int lo = bin * BINW, hi = lo + BINW;

  int s[8], d[8];
#pragma unroll
  for (int k = 0; k < 8; k++) {
    int e = t0 + k * stride;
    int ec = (e < GE) ? e : 0;
    s[k] = __builtin_nontemporal_load(&src[ec]);
    d[k] = __builtin_nontemporal_load(&dst[ec]);
    if (e >= GE) d[k] = -1;  // never matches any bin
  }
#pragma unroll
  for (int k = 0; k < 8; k++) {
    if (d[k] >= lo && d[k] < hi) {
      int slot = atomicAdd(&c[d[k]], 1);
      if (slot < CAP) bk[d[k] * CAP + slot] = (u16)s[k];
    }
  }
}

__global__ __launch_bounds__(256) void k_dinv(const int* __restrict__ cnt,
                                              float* __restrict__ dinv) {
  int i = blockIdx.x * 256 + threadIdx.x;
  if (i >= 2 * GN) return;
  dinv[i] = rsqrtf((float)(cnt[i] + 1));  // +1 self-loop
}

// Cast W (128x128 f32, W[k][n]) into MFMA B-fragment order:
// frag (kq,cb,lane), j-th elem = W[kq*32 + (lane>>4)*8 + j][cb*16 + (lane&15)]
// stored at Wf[((kq*8+cb)*64 + lane)*8 + j].
__global__ __launch_bounds__(256) void k_prep(const float* __restrict__ W0,
                                              const float* __restrict__ W1,
                                              u16* __restrict__ Wf0,
                                              u16* __restrict__ Wf1) {
  int idx = blockIdx.x * 256 + threadIdx.x;  // 0..4095
  const float* W = (idx & 2048) ? W1 : W0;
  u16* Wf = (idx & 2048) ? Wf1 : Wf0;
  int r = idx & 2047;
  int kq = r >> 9, cb = (r >> 6) & 7, lane = r & 63;
  int m16 = lane & 15, quad = lane >> 4;
  int k0 = kq * 32 + quad * 8;
  int n = cb * 16 + m16;
  u16x8 o;
#pragma unroll
  for (int j = 0; j < 8; j++) o[j] = f2bf(W[(k0 + j) * 128 + n]);
  *(u16x8*)&Wf[((kq * 8 + cb) * 64 + lane) * 8] = o;
}

// ---------------- bf16 MFMA GEMM, both graphs: H[2*GN][128] ----------------
// Grid = 2*782 blocks (was 782 = 76% of the 1024 block slots -> tail-bound;
// merged grid fills the machine). Per-block structure unchanged from round 5.
#define NB ((GN + 63) / 64)  // 782
template <bool IN_F32>
__global__ __launch_bounds__(256, 4) void k_gemm(const void* __restrict__ X1,
                                                 const void* __restrict__ X2,
                                                 const u16* __restrict__ Wf,
                                                 u16* __restrict__ H) {
  __shared__ u16 Xs[64][136];  // pad: row stride 272B, 16B-aligned frag reads
  int gb = blockIdx.x >= NB;
  int bid = blockIdx.x - gb * NB;
  const void* Xin = gb ? X2 : X1;
  u16* Hh = H + (size_t)gb * GN * GD;

  int t = threadIdx.x;
  int lane = t & 63, wave = t >> 6;
  int m16 = lane & 15, quad = lane >> 4;
  int r0 = bid * 64;

  bf16x8 bfr[4][2];
#pragma unroll
  for (int kq = 0; kq < 4; kq++)
#pragma unroll
    for (int c = 0; c < 2; c++)
      bfr[kq][c] = *(const bf16x8*)&Wf[((kq * 8 + wave * 2 + c) * 64 + lane) * 8];

  if (IN_F32) {  // stage + cast X tile (64 rows x 128 f32)
    const float4* Xv = (const float4*)Xin;
#pragma unroll
    for (int i = 0; i < 8; i++) {
      int idx = i * 256 + t;
      int row = idx >> 5, c4 = idx & 31;
      int gr = r0 + row; if (gr >= GN) gr = GN - 1;  // clamp; stores guarded
      float4 v = Xv[(size_t)gr * 32 + c4];
      u16x4 u; u.x = f2bf(v.x); u.y = f2bf(v.y); u.z = f2bf(v.z); u.w = f2bf(v.w);
      *(u16x4*)&Xs[row][c4 * 4] = u;
    }
  } else {  // bf16 input: straight u16x8 copy
    const u16x8* Xv = (const u16x8*)Xin;
#pragma unroll
    for (int i = 0; i < 4; i++) {
      int idx = i * 256 + t;
      int row = idx >> 4, c8 = idx & 15;
      int gr = r0 + row; if (gr >= GN) gr = GN - 1;
      *(u16x8*)&Xs[row][c8 * 8] = Xv[(size_t)gr * 16 + c8];
    }
  }
  __syncthreads();

  f32x4 acc[4][2] = {};
#pragma unroll
  for (int kq = 0; kq < 4; kq++) {
#pragma unroll
    for (int rb = 0; rb < 4; rb++) {
      bf16x8 a = *(const bf16x8*)&Xs[rb * 16 + m16][kq * 32 + quad * 8];
      acc[rb][0] = __builtin_amdgcn_mfma_f32_16x16x32_bf16(a, bfr[kq][0], acc[rb][0], 0, 0, 0);
      acc[rb][1] = __builtin_amdgcn_mfma_f32_16x16x32_bf16(a, bfr[kq][1], acc[rb][1], 0, 0, 0);
    }
  }

#pragma unroll
  for (int rb = 0; rb < 4; rb++) {
#pragma unroll
    for (int i = 0; i < 4; i++) {
      int grow = r0 + rb * 16 + quad * 4 + i;
      if (grow < GN) {
#pragma unroll
        for (int c = 0; c < 2; c++)
          Hh[(size_t)grow * 128 + (wave * 2 + c) * 16 + m16] = f2bf(acc[rb][c][i]);
      }
    }
  }
}

// ---------------- aggregation, both graphs ----------------
// One wave per node (2*GN waves). Per-edge src/weight via readlane; 16
// independent row-gathers in flight; pad lanes (weight 0) gather row 0.
template <bool FINAL>  // FINAL: f32 out, no relu. else: bf16 out + relu.
__global__ __launch_bounds__(256) void k_agg(const u16* __restrict__ H,
                                             const u16* __restrict__ bucket,
                                             const int* __restrict__ cnt,
                                             const float* __restrict__ dinv,
                                             const float* __restrict__ bias,
                                             void* __restrict__ out) {
  int widg = (blockIdx.x * 256 + threadIdx.x) >> 6;  // 0..2*GN-1
  int lane = threadIdx.x & 63;
  if (widg >= 2 * GN) return;
  int gb = widg >= GN;
  int wid = widg - gb * GN;

  const int* c = cnt + gb * GN;
  const float* dvp = dinv + gb * GN;
  const u16* bk = bucket + (size_t)gb * GN * CAP;
  const u32* Hv = (const u32*)H + (size_t)gb * GN * 64;

  float dv = dvp[wid];
  int deg = min(c[wid], CAP);

  int s_l = 0;
  float d_l = 0.f;
  if (lane < deg) {  // coalesced preload; padded lanes: row 0 with weight 0
    s_l = (int)bk[wid * CAP + lane];
    d_l = dvp[s_l];
  }

  u32 hs = Hv[(size_t)wid * 64 + lane];
  float ax = dv * bf2f_lo(hs);
  float ay = dv * bf2f_hi(hs);
  float2 bb = ((const float2*)bias)[lane];

  int dpad = (deg + 15) & ~15;
  for (int i = 0; i < dpad; i += 16) {
    int ss[16];
    u32 hh[16];
    float ww[16];
#pragma unroll
    for (int j = 0; j < 16; j++) ss[j] = __builtin_amdgcn_readlane(s_l, i + j);
#pragma unroll
    for (int j = 0; j < 16; j++) hh[j] = Hv[(size_t)ss[j] * 64 + lane];
#pragma unroll
    for (int j = 0; j < 16; j++) ww[j] = rlf(d_l, i + j);
#pragma unroll
    for (int j = 0; j < 16; j++) {
      ax += ww[j] * bf2f_lo(hh[j]);
      ay += ww[j] * bf2f_hi(hh[j]);
    }
  }

  float ox = dv * ax + bb.x;
  float oy = dv * ay + bb.y;
  if (!FINAL) {
    ox = fmaxf(ox, 0.f); oy = fmaxf(oy, 0.f);
    u32 packed = ((u32)f2bf(oy) << 16) | (u32)f2bf(ox);
    ((u32*)out)[(size_t)widg * 64 + lane] = packed;
  } else {  // widg spans both graphs; d_out is z1||z2, so index directly
    ((float2*)out)[(size_t)widg * 64 + lane] = make_float2(ox, oy);
  }
}

extern "C" void kernel_launch(void* const* d_in, const int* in_sizes, int n_in,
                              void* d_out, int out_size, void* d_ws, size_t ws_size,
                              hipStream_t stream) {
  const float* x1 = (const float*)d_in[0];
  const int* ei1  = (const int*)d_in[1];
  const float* x2 = (const float*)d_in[2];
  const int* ei2  = (const int*)d_in[3];
  const float* W0 = (const float*)d_in[4];
  const float* b0 = (const float*)d_in[5];
  const float* W1 = (const float*)d_in[6];
  const float* b1 = (const float*)d_in[7];
  float* out = (float*)d_out;

  char* ws = (char*)d_ws;
  size_t off = 0;
  auto carve = [&](size_t bytes) -> char* {
    char* p = ws + off;
    off = (off + bytes + 511) & ~(size_t)511;
    return p;
  };
  int* cnt    = (int*)carve((size_t)2 * GN * 4);
  float* dinv = (float*)carve((size_t)2 * GN * 4);
  u16* bucket = (u16*)carve((size_t)2 * GN * CAP * 2);  // 12.8 MB
  u16* h      = (u16*)carve((size_t)2 * GN * GD * 2);   // 25.6 MB
  u16* a      = (u16*)carve((size_t)2 * GN * GD * 2);   // 25.6 MB
  u16* W0f    = (u16*)carve((size_t)GD * GD * 2);
  u16* W1f    = (u16*)carve((size_t)GD * GD * 2);

  k_prep<<<16, 256, 0, stream>>>(W0, W1, W0f, W1f);
  hipMemsetAsync(cnt, 0, (size_t)2 * GN * 4, stream);
  k_build<<<2 * NBIN * NCHUNK, 256, 0, stream>>>(ei1, ei2, cnt, bucket);
  k_dinv<<<(2 * GN + 255) / 256, 256, 0, stream>>>(cnt, dinv);

  // Layer 1 (both graphs): a = relu(Ahat * (x @ W0) + b0)   [a bf16, 2*GN rows]
  k_gemm<true><<<2 * NB, 256, 0, stream>>>(x1, x2, W0f, h);
  k_agg<false><<<(2 * GN * 64 + 255) / 256, 256, 0, stream>>>(h, bucket, cnt, dinv, b0, a);

  // Layer 2 (both graphs): z = Ahat * (a @ W1) + b1          [f32 -> d_out]
  k_gemm<false><<<2 * NB, 256, 0, stream>>>(a, a + (size_t)GN * GD, W1f, h);
  k_agg<true><<<(2 * GN * 64 + 255) / 256, 256, 0, stream>>>(h, bucket, cnt, dinv, b1, out);
}